// Round 1
// baseline (217.278 us; speedup 1.0000x reference)
//
#include <hip/hip_runtime.h>

// Problem: B=8, C=16, H=W=384. Three fp32 inputs [B,C,H,W]:
//   net_out, target, max_positiones (setup_inputs dict order).
// Output: single fp32 scalar.
//
// loss_bc = 0.05*m1/(d1+eps) + 0.95*m2/(d2+eps)
//   m1 = sum(diff2*t), d1 = sum(t), m2 = sum(diff2*(1-t)), d2 = sum(1-t)
// active_bc = !(max(t)==0 && max(mp)==0); losses = active ? loss : 0
// img_loss_b = sum_c(losses) / count_nonzero_c(losses); out = mean_b(img_loss)

#define B_DIM 8
#define C_DIM 16
#define HW 147456            // 384*384
#define SEGS 16
#define SEG_ELEMS (HW / SEGS)        // 9216
#define TPB 256
#define F4_PER_THREAD (SEG_ELEMS / 4 / TPB)  // 9

#define ALPHA 0.05f
#define SMOOTH 1e-6f

__global__ __launch_bounds__(TPB) void mismatch_partial_kernel(
    const float* __restrict__ net_out,
    const float* __restrict__ target,
    const float* __restrict__ maxp,
    float* __restrict__ ws)
{
    const int blk = blockIdx.x;          // [0, B*C*SEGS)
    const int bc  = blk >> 4;            // slice index
    const int seg = blk & (SEGS - 1);
    const size_t base = (size_t)bc * HW + (size_t)seg * SEG_ELEMS;

    const float4* __restrict__ n4 = (const float4*)(net_out + base);
    const float4* __restrict__ t4 = (const float4*)(target + base);
    const float4* __restrict__ m4 = (const float4*)(maxp + base);

    const int tid = threadIdx.x;

    float sum_t = 0.f, m1 = 0.f, m2 = 0.f, mx_t = 0.f, mx_m = 0.f;

#pragma unroll
    for (int k = 0; k < F4_PER_THREAD; ++k) {
        const int idx = k * TPB + tid;   // coalesced float4 access
        const float4 tv = t4[idx];
        const float4 nv = n4[idx];
        const float4 mv = m4[idx];

        float d, d2;
        d = tv.x - nv.x; d2 = d * d;
        sum_t += tv.x; m1 += d2 * tv.x; m2 += d2 * (1.f - tv.x);
        mx_t = fmaxf(mx_t, tv.x); mx_m = fmaxf(mx_m, mv.x);

        d = tv.y - nv.y; d2 = d * d;
        sum_t += tv.y; m1 += d2 * tv.y; m2 += d2 * (1.f - tv.y);
        mx_t = fmaxf(mx_t, tv.y); mx_m = fmaxf(mx_m, mv.y);

        d = tv.z - nv.z; d2 = d * d;
        sum_t += tv.z; m1 += d2 * tv.z; m2 += d2 * (1.f - tv.z);
        mx_t = fmaxf(mx_t, tv.z); mx_m = fmaxf(mx_m, mv.z);

        d = tv.w - nv.w; d2 = d * d;
        sum_t += tv.w; m1 += d2 * tv.w; m2 += d2 * (1.f - tv.w);
        mx_t = fmaxf(mx_t, tv.w); mx_m = fmaxf(mx_m, mv.w);
    }

    // wave (64-lane) reduction
#pragma unroll
    for (int off = 32; off > 0; off >>= 1) {
        sum_t += __shfl_down(sum_t, off);
        m1    += __shfl_down(m1, off);
        m2    += __shfl_down(m2, off);
        mx_t   = fmaxf(mx_t, __shfl_down(mx_t, off));
        mx_m   = fmaxf(mx_m, __shfl_down(mx_m, off));
    }

    __shared__ float s[4][5];
    const int wave = tid >> 6;
    const int lane = tid & 63;
    if (lane == 0) {
        s[wave][0] = sum_t; s[wave][1] = m1; s[wave][2] = m2;
        s[wave][3] = mx_t;  s[wave][4] = mx_m;
    }
    __syncthreads();
    if (tid == 0) {
        float a = 0.f, b = 0.f, c = 0.f, d = 0.f, e = 0.f;
#pragma unroll
        for (int w = 0; w < 4; ++w) {
            a += s[w][0]; b += s[w][1]; c += s[w][2];
            d = fmaxf(d, s[w][3]); e = fmaxf(e, s[w][4]);
        }
        float* o = ws + (size_t)blk * 5;
        o[0] = a; o[1] = b; o[2] = c; o[3] = d; o[4] = e;
    }
}

__global__ __launch_bounds__(128) void mismatch_final_kernel(
    const float* __restrict__ ws, float* __restrict__ out)
{
    __shared__ float losses[B_DIM * C_DIM];
    __shared__ float img[B_DIM];
    const int tid = threadIdx.x;

    if (tid < B_DIM * C_DIM) {
        float sum_t = 0.f, m1 = 0.f, m2 = 0.f, mx_t = 0.f, mx_m = 0.f;
#pragma unroll
        for (int s = 0; s < SEGS; ++s) {
            const float* p = ws + ((size_t)tid * SEGS + s) * 5;
            sum_t += p[0]; m1 += p[1]; m2 += p[2];
            mx_t = fmaxf(mx_t, p[3]); mx_m = fmaxf(mx_m, p[4]);
        }
        const float d1 = sum_t;
        const float d2 = (float)HW - sum_t;   // sum(1 - t)
        const float loss = ALPHA * m1 / (d1 + SMOOTH)
                         + (1.f - ALPHA) * m2 / (d2 + SMOOTH);
        const bool active = !((mx_t == 0.f) && (mx_m == 0.f));
        losses[tid] = active ? loss : 0.f;
    }
    __syncthreads();
    if (tid < B_DIM) {
        float s = 0.f; int cnt = 0;
#pragma unroll
        for (int c = 0; c < C_DIM; ++c) {
            const float l = losses[tid * C_DIM + c];
            s += l;
            cnt += (l != 0.f) ? 1 : 0;
        }
        img[tid] = s / (float)cnt;   // NaN if cnt==0, matching 0/0 in reference
    }
    __syncthreads();
    if (tid == 0) {
        float s = 0.f;
#pragma unroll
        for (int b = 0; b < B_DIM; ++b) s += img[b];
        out[0] = s / (float)B_DIM;
    }
}

extern "C" void kernel_launch(void* const* d_in, const int* in_sizes, int n_in,
                              void* d_out, int out_size, void* d_ws, size_t ws_size,
                              hipStream_t stream) {
    const float* net_out = (const float*)d_in[0];
    const float* target  = (const float*)d_in[1];
    const float* maxp    = (const float*)d_in[2];
    float* out = (float*)d_out;
    float* ws  = (float*)d_ws;   // needs B*C*SEGS*5*4 = 40 KB

    const int nblocks = B_DIM * C_DIM * SEGS;   // 2048
    mismatch_partial_kernel<<<nblocks, TPB, 0, stream>>>(net_out, target, maxp, ws);
    mismatch_final_kernel<<<1, 128, 0, stream>>>(ws, out);
}

// Round 2
// 199.330 us; speedup vs baseline: 1.0900x; 1.0900x over previous
//
#include <hip/hip_runtime.h>

// B=8, C=16, H=W=384. Inputs (fp32): net_out, target, max_positiones.
// loss_bc = 0.05*m1/(d1+eps) + 0.95*m2/(d2+eps)
//   m1 = sum(d2*t), d1 = sum(t), m2 = sum(d2) - m1, d2sum tracked, d2den = HW - d1
// active_bc = !(max(t)==0 && max(mp)==0)  -> mp only read if max(t)==0 (pass B)
// img_loss_b = sum_c(losses)/count_nonzero(losses); out = mean_b.

#define B_DIM 8
#define C_DIM 16
#define BC    (B_DIM * C_DIM)        // 128
#define HW    147456                 // 384*384
#define SEGS  16
#define SEG_ELEMS (HW / SEGS)        // 9216
#define TPB   256
#define F4PT  (SEG_ELEMS / 4 / TPB)  // 9 float4 per thread per array
#define NBLK  (BC * SEGS)            // 2048

#define ALPHA  0.05f
#define SMOOTH 1e-6f

// ws layout (floats, SoA): [q*NBLK + blk]
//   q=0: sum_t   q=1: m1   q=2: sum_d2   q=3: mx_t   q=4: mx_m (pass B, conditional)

__global__ __launch_bounds__(TPB, 2) void mismatch_passA(
    const float* __restrict__ net_out,
    const float* __restrict__ target,
    float* __restrict__ ws)
{
    const int blk = blockIdx.x;                       // [0, NBLK)
    const size_t base4 = (size_t)blk * (SEG_ELEMS / 4);
    const int tid = threadIdx.x;

    const float4* __restrict__ t4 = (const float4*)target + base4;
    const float4* __restrict__ n4 = (const float4*)net_out + base4;

    // Issue all loads up front -> 18 in-flight 16B loads per thread (MLP).
    float4 tv[F4PT], nv[F4PT];
#pragma unroll
    for (int k = 0; k < F4PT; ++k) {
        tv[k] = t4[k * TPB + tid];
        nv[k] = n4[k * TPB + tid];
    }

    float sum_t = 0.f, m1 = 0.f, sd2 = 0.f, mxt = 0.f;
#pragma unroll
    for (int k = 0; k < F4PT; ++k) {
#define ACC(c) { float t = tv[k].c, n = nv[k].c;          \
                 float d = t - n; float d2 = d * d;       \
                 sum_t += t; sd2 += d2;                   \
                 m1 = fmaf(d2, t, m1); mxt = fmaxf(mxt, t); }
        ACC(x) ACC(y) ACC(z) ACC(w)
#undef ACC
    }

    // wave reduction (64 lanes)
#pragma unroll
    for (int off = 32; off > 0; off >>= 1) {
        sum_t += __shfl_down(sum_t, off);
        m1    += __shfl_down(m1, off);
        sd2   += __shfl_down(sd2, off);
        mxt    = fmaxf(mxt, __shfl_down(mxt, off));
    }

    __shared__ float s[4][4];
    const int wave = tid >> 6, lane = tid & 63;
    if (lane == 0) { s[wave][0] = sum_t; s[wave][1] = m1; s[wave][2] = sd2; s[wave][3] = mxt; }
    __syncthreads();
    if (tid == 0) {
        float a = 0.f, b = 0.f, c = 0.f, d = 0.f;
#pragma unroll
        for (int w = 0; w < 4; ++w) {
            a += s[w][0]; b += s[w][1]; c += s[w][2]; d = fmaxf(d, s[w][3]);
        }
        ws[0 * NBLK + blk] = a;
        ws[1 * NBLK + blk] = b;
        ws[2 * NBLK + blk] = c;
        ws[3 * NBLK + blk] = d;
    }
}

// Pass B: only touches max_positiones for (b,c) slices whose max(target)==0.
// For such a slice, every one of its 16 seg-blocks reads its segment of mp.
__global__ __launch_bounds__(TPB) void mismatch_passB(
    const float* __restrict__ maxp,
    float* __restrict__ ws)
{
    const int blk = blockIdx.x;
    const int bc  = blk >> 4;
    const int tid = threadIdx.x;

    // Fold this slice's 16 per-seg target-maxes (wave-uniform broadcast reads).
    const float* mxt_p = ws + 3 * NBLK + (bc << 4);
    float mt = 0.f;
#pragma unroll
    for (int i = 0; i < 16; ++i) mt = fmaxf(mt, mxt_p[i]);
    if (mt != 0.f) return;   // uniform exit: mp irrelevant for this slice

    const size_t base4 = (size_t)blk * (SEG_ELEMS / 4);
    const float4* __restrict__ m4 = (const float4*)maxp + base4;

    float4 mv[F4PT];
#pragma unroll
    for (int k = 0; k < F4PT; ++k) mv[k] = m4[k * TPB + tid];

    float mx = 0.f;
#pragma unroll
    for (int k = 0; k < F4PT; ++k)
        mx = fmaxf(mx, fmaxf(fmaxf(mv[k].x, mv[k].y), fmaxf(mv[k].z, mv[k].w)));

#pragma unroll
    for (int off = 32; off > 0; off >>= 1)
        mx = fmaxf(mx, __shfl_down(mx, off));

    __shared__ float s[4];
    const int wave = tid >> 6, lane = tid & 63;
    if (lane == 0) s[wave] = mx;
    __syncthreads();
    if (tid == 0)
        ws[4 * NBLK + blk] = fmaxf(fmaxf(s[0], s[1]), fmaxf(s[2], s[3]));
}

__global__ __launch_bounds__(128) void mismatch_final(
    const float* __restrict__ ws, float* __restrict__ out)
{
    __shared__ float losses[BC];
    __shared__ float img[B_DIM];
    const int tid = threadIdx.x;   // one thread per (b,c)

    {
        float sum_t = 0.f, m1 = 0.f, sd2 = 0.f, mxt = 0.f, mxm = 0.f;
#pragma unroll
        for (int s = 0; s < SEGS; ++s) {
            const int i = (tid << 4) + s;
            sum_t += ws[0 * NBLK + i];
            m1    += ws[1 * NBLK + i];
            sd2   += ws[2 * NBLK + i];
            mxt    = fmaxf(mxt, ws[3 * NBLK + i]);
            mxm    = fmaxf(mxm, ws[4 * NBLK + i]);  // poison-garbage unless mxt==0 (then real)
        }
        const float m2 = sd2 - m1;
        const float d1 = sum_t;
        const float d2 = (float)HW - sum_t;
        const float loss = ALPHA * m1 / (d1 + SMOOTH)
                         + (1.f - ALPHA) * m2 / (d2 + SMOOTH);
        // mxm only consulted when mxt==0, in which case pass B wrote it.
        const bool inactive = (mxt == 0.f) && (mxm == 0.f);
        losses[tid] = inactive ? 0.f : loss;
    }
    __syncthreads();
    if (tid < B_DIM) {
        float s = 0.f; int cnt = 0;
#pragma unroll
        for (int c = 0; c < C_DIM; ++c) {
            const float l = losses[tid * C_DIM + c];
            s += l;
            cnt += (l != 0.f) ? 1 : 0;
        }
        img[tid] = s / (float)cnt;   // 0/0 -> NaN matches reference
    }
    __syncthreads();
    if (tid == 0) {
        float s = 0.f;
#pragma unroll
        for (int b = 0; b < B_DIM; ++b) s += img[b];
        out[0] = s / (float)B_DIM;
    }
}

extern "C" void kernel_launch(void* const* d_in, const int* in_sizes, int n_in,
                              void* d_out, int out_size, void* d_ws, size_t ws_size,
                              hipStream_t stream) {
    const float* net_out = (const float*)d_in[0];
    const float* target  = (const float*)d_in[1];
    const float* maxp    = (const float*)d_in[2];
    float* out = (float*)d_out;
    float* ws  = (float*)d_ws;   // needs 5*NBLK*4 = 40 KB

    mismatch_passA<<<NBLK, TPB, 0, stream>>>(net_out, target, ws);
    mismatch_passB<<<NBLK, TPB, 0, stream>>>(maxp, ws);
    mismatch_final<<<1, 128, 0, stream>>>(ws, out);
}

// Round 3
// 193.217 us; speedup vs baseline: 1.1245x; 1.0316x over previous
//
#include <hip/hip_runtime.h>

// B=8, C=16, H=W=384. Inputs (fp32): net_out, target, max_positiones.
// loss_bc = 0.05*m1/(d1+eps) + 0.95*m2/(d2+eps)
//   m1 = sum(d2*t), d1 = sum(t), m2 = sum(d2) - m1, d2den = HW - d1
// active_bc = !(max(t)==0 && max(mp)==0) -> mp scanned only if max(t)==0 (rare path, final kernel)
// img_loss_b = sum_c(losses)/count_nonzero(losses); out = mean_b.

#define B_DIM 8
#define C_DIM 16
#define BC    (B_DIM * C_DIM)        // 128
#define HW    147456                 // 384*384
#define SEGS  16
#define SEG_ELEMS (HW / SEGS)        // 9216
#define TPB   256
#define F4PT  (SEG_ELEMS / 4 / TPB)  // 9 float4 per thread per array
#define NBLK  (BC * SEGS)            // 2048

#define ALPHA  0.05f
#define SMOOTH 1e-6f

// ws layout: float4 per block: {sum_t, m1, sum_d2, mx_t}

__global__ __launch_bounds__(TPB, 2) void mismatch_passA(
    const float* __restrict__ net_out,
    const float* __restrict__ target,
    float4* __restrict__ ws)
{
    const int blk = blockIdx.x;                       // [0, NBLK)
    const size_t base4 = (size_t)blk * (SEG_ELEMS / 4);
    const int tid = threadIdx.x;

    const float4* __restrict__ t4 = (const float4*)target + base4;
    const float4* __restrict__ n4 = (const float4*)net_out + base4;

    // Load phase: all 18 float4 loads issued before ANY compute.
    float4 tv[F4PT], nv[F4PT];
#pragma unroll
    for (int k = 0; k < F4PT; ++k) tv[k] = t4[k * TPB + tid];
#pragma unroll
    for (int k = 0; k < F4PT; ++k) nv[k] = n4[k * TPB + tid];

    // Hard scheduling fence: compiler may not sink the loads past this point.
    __builtin_amdgcn_sched_barrier(0);

    float sum_t = 0.f, m1 = 0.f, sd2 = 0.f, mxt = 0.f;
#pragma unroll
    for (int k = 0; k < F4PT; ++k) {
#define ACC(c) { float t = tv[k].c, n = nv[k].c;          \
                 float d = t - n; float d2 = d * d;       \
                 sum_t += t; sd2 += d2;                   \
                 m1 = fmaf(d2, t, m1); mxt = fmaxf(mxt, t); }
        ACC(x) ACC(y) ACC(z) ACC(w)
#undef ACC
    }

    // wave (64-lane) reduction
#pragma unroll
    for (int off = 32; off > 0; off >>= 1) {
        sum_t += __shfl_down(sum_t, off);
        m1    += __shfl_down(m1, off);
        sd2   += __shfl_down(sd2, off);
        mxt    = fmaxf(mxt, __shfl_down(mxt, off));
    }

    __shared__ float s[4][4];
    const int wave = tid >> 6, lane = tid & 63;
    if (lane == 0) { s[wave][0] = sum_t; s[wave][1] = m1; s[wave][2] = sd2; s[wave][3] = mxt; }
    __syncthreads();
    if (tid == 0) {
        float4 o;
        o.x = s[0][0] + s[1][0] + s[2][0] + s[3][0];
        o.y = s[0][1] + s[1][1] + s[2][1] + s[3][1];
        o.z = s[0][2] + s[1][2] + s[2][2] + s[3][2];
        o.w = fmaxf(fmaxf(s[0][3], s[1][3]), fmaxf(s[2][3], s[3][3]));
        ws[blk] = o;
    }
}

__global__ __launch_bounds__(128) void mismatch_final(
    const float4* __restrict__ ws,
    const float* __restrict__ maxp,
    float* __restrict__ out)
{
    __shared__ float losses[BC];
    __shared__ float img[B_DIM];
    const int tid = threadIdx.x;   // one thread per (b,c) slice

    {
        float sum_t = 0.f, m1 = 0.f, sd2 = 0.f, mxt = 0.f;
#pragma unroll
        for (int s = 0; s < SEGS; ++s) {
            const float4 v = ws[(tid << 4) + s];
            sum_t += v.x; m1 += v.y; sd2 += v.z; mxt = fmaxf(mxt, v.w);
        }
        bool inactive = false;
        if (mxt == 0.f) {
            // Rare path: slice's target is all-zero; must consult max_positiones.
            const float4* m4 = (const float4*)maxp + (size_t)tid * (HW / 4);
            float mx = 0.f;
            for (int i = 0; i < HW / 4; ++i) {
                const float4 v = m4[i];
                mx = fmaxf(mx, fmaxf(fmaxf(v.x, v.y), fmaxf(v.z, v.w)));
            }
            inactive = (mx == 0.f);
        }
        const float m2 = sd2 - m1;
        const float d1 = sum_t;
        const float d2 = (float)HW - sum_t;
        const float loss = ALPHA * m1 / (d1 + SMOOTH)
                         + (1.f - ALPHA) * m2 / (d2 + SMOOTH);
        losses[tid] = inactive ? 0.f : loss;
    }
    __syncthreads();
    if (tid < B_DIM) {
        float s = 0.f; int cnt = 0;
#pragma unroll
        for (int c = 0; c < C_DIM; ++c) {
            const float l = losses[tid * C_DIM + c];
            s += l;
            cnt += (l != 0.f) ? 1 : 0;
        }
        img[tid] = s / (float)cnt;   // 0/0 -> NaN matches reference
    }
    __syncthreads();
    if (tid == 0) {
        float s = 0.f;
#pragma unroll
        for (int b = 0; b < B_DIM; ++b) s += img[b];
        out[0] = s / (float)B_DIM;
    }
}

extern "C" void kernel_launch(void* const* d_in, const int* in_sizes, int n_in,
                              void* d_out, int out_size, void* d_ws, size_t ws_size,
                              hipStream_t stream) {
    const float* net_out = (const float*)d_in[0];
    const float* target  = (const float*)d_in[1];
    const float* maxp    = (const float*)d_in[2];
    float* out = (float*)d_out;
    float4* ws = (float4*)d_ws;   // needs NBLK*16 = 32 KB

    mismatch_passA<<<NBLK, TPB, 0, stream>>>(net_out, target, ws);
    mismatch_final<<<1, 128, 0, stream>>>(ws, maxp, out);
}